// Round 7
// baseline (180.685 us; speedup 1.0000x reference)
//
#include <hip/hip_runtime.h>

#define DIM_ 1024
#define NH_ 16
#define HD_ 64
#define B_ 2
#define S_ 2048
#define M_ (B_ * S_)      // 4096
#define NQKV_ (3 * DIM_)  // 3072

typedef __attribute__((ext_vector_type(8))) __bf16 bf16x8;
typedef __attribute__((ext_vector_type(4))) __bf16 bf16x4;
typedef __attribute__((ext_vector_type(4))) float f32x4;

__device__ __forceinline__ void gl_lds16(const void* g, void* l) {
  __builtin_amdgcn_global_load_lds(
      (__attribute__((address_space(1))) void*)const_cast<void*>(g),
      (__attribute__((address_space(3))) void*)l, 16, 0, 0);
}

// ---------------- fused cast fp32 -> bf16 for x, qkv_w, proj_w ----------------
#define N4_X 1048576   // 4096*1024/4
#define N4_W1 786432   // 3072*1024/4
#define N4_W2 262144   // 1024*1024/4
__global__ __launch_bounds__(256) void cast_all(const float* __restrict__ x,
                                                const float* __restrict__ w1,
                                                const float* __restrict__ w2,
                                                __bf16* __restrict__ xb,
                                                __bf16* __restrict__ w1b,
                                                __bf16* __restrict__ w2b) {
  int i = blockIdx.x * 256 + threadIdx.x;
  const int stride = gridDim.x * 256;
  for (; i < N4_X + N4_W1 + N4_W2; i += stride) {
    const float4* src;
    bf16x4* dst;
    int j;
    if (i < N4_X) { src = (const float4*)x; dst = (bf16x4*)xb; j = i; }
    else if (i < N4_X + N4_W1) { src = (const float4*)w1; dst = (bf16x4*)w1b; j = i - N4_X; }
    else { src = (const float4*)w2; dst = (bf16x4*)w2b; j = i - (N4_X + N4_W1); }
    float4 v = src[j];
    bf16x4 o;
    o[0] = (__bf16)v.x; o[1] = (__bf16)v.y; o[2] = (__bf16)v.z; o[3] = (__bf16)v.w;
    dst[j] = o;
  }
}

// ---------------- BMx128 bf16 MFMA GEMM, BK=64, double-buffered, 512 threads ----------------
// Y[m][n] = sum_k A[m][k] * Bw[n][k]  (+ bias[n])
// 8 waves: wm=wave>>1 (4 m-positions of MT*16 rows), wn=wave&1 (2 n-positions of 64).
// LDS tiles [BM|128][64] x2 buffers, 16B-chunk XOR swizzle: chunk (r,c) at column c^(r&7).
// Single barrier per kt: prefetch kt+1 into buf^1, compute from buf (R5 attn pattern —
// the barrier's vmcnt drain then waits on loads issued a full compute phase earlier).
// MODE 0 (BM=128): scatter Q (scaled 0.125*log2e), K as [bh][s][64]; V transposed+
//         key-permuted into Vt[bh][dh][slot] (slot = 32a+8q+4b+r for s=32a+16b+4q+r).
// MODE 1 (BM=64): write fp32 Cout[m][n] = Y + bias  (more blocks for short-N proj)
template <int MODE, int BM>
__global__ __launch_bounds__(512, 4) void gemm_bt(const __bf16* __restrict__ A,
                                                  const __bf16* __restrict__ Bw,
                                                  const float* __restrict__ bias,
                                                  __bf16* __restrict__ Qp, __bf16* __restrict__ Kp,
                                                  __bf16* __restrict__ Vt,
                                                  float* __restrict__ Cout) {
  constexpr int KD = 1024;
  constexpr int BN = 128;
  constexpr int MT = BM / 64;          // m-tiles (of 16 rows) per wave
  constexpr int NC = (BM + BN) / 64;   // 16B chunks staged per thread
  constexpr int NA = BM / 64;          // of which A-chunks (i < NA)
  constexpr int NKT = KD / 64;
  __shared__ __bf16 As[2][BM * 64];
  __shared__ __bf16 Bs[2][BN * 64];
  const int tid = threadIdx.x;
  const int lane = tid & 63;
  const int wave = tid >> 6;  // 0..7
  const int quad = lane >> 4;
  const int r16 = lane & 15;
  const int wm = wave >> 1;   // 0..3
  const int wn = wave & 1;    // 0..1
  const int m0 = blockIdx.y * BM;
  const int n0 = blockIdx.x * BN;

  const f32x4 fz = {0.f, 0.f, 0.f, 0.f};
  f32x4 acc[MT][4];
#pragma unroll
  for (int i = 0; i < MT; ++i)
#pragma unroll
    for (int j = 0; j < 4; ++j) acc[i][j] = fz;

  // staging: chunk i<NA -> As (chunk id tid+i*512), else -> Bs (chunk id tid+(i-NA)*512)
  const __bf16* gp[NC];
  int lofs[NC];
#pragma unroll
  for (int i = 0; i < NC; ++i) {
    if (i < NA) {
      const int c = tid + i * 512;
      const int r = c >> 3, cc = c & 7;
      gp[i] = A + (size_t)(m0 + r) * KD + ((cc ^ (r & 7)) * 8);
      lofs[i] = c * 8;
    } else {
      const int c = tid + (i - NA) * 512;
      const int r = c >> 3, cc = c & 7;
      gp[i] = Bw + (size_t)(n0 + r) * KD + ((cc ^ (r & 7)) * 8);
      lofs[i] = c * 8;
    }
  }

  // prefetch tile 0 into buffer 0
#pragma unroll
  for (int i = 0; i < NC; ++i) {
    gl_lds16(gp[i], (i < NA) ? &As[0][lofs[i]] : &Bs[0][lofs[i]]);
    gp[i] += 64;
  }

  for (int kt = 0; kt < NKT; ++kt) {
    const int cb = kt & 1;
    __syncthreads();  // drains prefetch of tile kt; frees buffer cb^1 (read in kt-1)
    if (kt + 1 < NKT) {
#pragma unroll
      for (int i = 0; i < NC; ++i) {
        gl_lds16(gp[i], (i < NA) ? &As[cb ^ 1][lofs[i]] : &Bs[cb ^ 1][lofs[i]]);
        gp[i] += 64;
      }
    }

#pragma unroll
    for (int sub = 0; sub < 2; ++sub) {
      const int ch = ((sub * 4 + quad) ^ (r16 & 7)) * 8;
      bf16x8 af[MT], bfr[4];
#pragma unroll
      for (int mt = 0; mt < MT; ++mt)
        af[mt] = *(const bf16x8*)&As[cb][(wm * MT * 16 + mt * 16 + r16) * 64 + ch];
#pragma unroll
      for (int nt = 0; nt < 4; ++nt)
        bfr[nt] = *(const bf16x8*)&Bs[cb][(wn * 64 + nt * 16 + r16) * 64 + ch];
#pragma unroll
      for (int mt = 0; mt < MT; ++mt)
#pragma unroll
        for (int nt = 0; nt < 4; ++nt)
          acc[mt][nt] =
              __builtin_amdgcn_mfma_f32_16x16x32_bf16(af[mt], bfr[nt], acc[mt][nt], 0, 0, 0);
    }
  }

  if (MODE == 0) {
#pragma unroll
    for (int nt = 0; nt < 4; ++nt) {
      const int n = n0 + wn * 64 + nt * 16 + r16;
      const int sel = n >> 10;  // wave-uniform (n range is 64-aligned, 64-wide)
      const int h = (n >> 6) & 15;
      const int dh = n & 63;
      const float bs = bias[n];
      if (sel == 2) {
        // V: transposed + key-permuted; 4 consecutive s -> contiguous slots -> bf16x4
#pragma unroll
        for (int mt = 0; mt < MT; ++mt) {
          const int m = m0 + wm * MT * 16 + mt * 16 + quad * 4;
          const int b = m >> 11;
          const int s = m & 2047;
          const int slot = (s & ~31) | (((s >> 2) & 3) << 3) | (((s >> 4) & 1) << 2);
          bf16x4 ov;
#pragma unroll
          for (int r = 0; r < 4; ++r) ov[r] = (__bf16)(acc[mt][nt][r] + bs);
          *(bf16x4*)&Vt[((size_t)((b * NH_ + h) * HD_ + dh)) * S_ + slot] = ov;
        }
      } else {
        __bf16* dst = (sel == 0) ? Qp : Kp;
        // fold softmax scale AND log2(e) into Q: softmax uses 2^s afterwards
        const float mul = (sel == 0) ? 0.18033688011112042f : 1.0f;
#pragma unroll
        for (int mt = 0; mt < MT; ++mt) {
#pragma unroll
          for (int r = 0; r < 4; ++r) {
            const int m = m0 + wm * MT * 16 + mt * 16 + quad * 4 + r;
            const int b = m >> 11;
            const int s = m & 2047;
            dst[((size_t)((b * NH_ + h) * S_ + s)) * HD_ + dh] =
                (__bf16)((acc[mt][nt][r] + bs) * mul);
          }
        }
      }
    }
  } else {
#pragma unroll
    for (int nt = 0; nt < 4; ++nt) {
      const int n = n0 + wn * 64 + nt * 16 + r16;
      const float bs = bias[n];
#pragma unroll
      for (int mt = 0; mt < MT; ++mt) {
#pragma unroll
        for (int r = 0; r < 4; ++r) {
          const int m = m0 + wm * MT * 16 + mt * 16 + quad * 4 + r;
          Cout[(size_t)m * DIM_ + n] = acc[mt][nt][r] + bs;
        }
      }
    }
  }
}

// ---------------- flash attention, S^T form, 8 waves x 16q, double-buffered ----------------
// (unchanged from R5) grid (S/128, B*H); block 512. Q pre-scaled by 0.125*log2e;
// p = 2^s raw; P in registers; O^T = V^T P^T.
__global__ __launch_bounds__(512) void attn(const __bf16* __restrict__ Qp,
                                            const __bf16* __restrict__ Kp,
                                            const __bf16* __restrict__ Vtp,
                                            __bf16* __restrict__ ctx) {
  __shared__ __bf16 Ks[2][128 * 64];
  __shared__ __bf16 Vs[2][64 * 128];
  const int tid = threadIdx.x;
  const int lane = tid & 63;
  const int wave = tid >> 6;
  const int quad = lane >> 4;
  const int r16 = lane & 15;
  const int bh = blockIdx.y;
  const int q0 = blockIdx.x * 128;
  const int qrow = q0 + wave * 16 + r16;

  const __bf16* qb = Qp + ((size_t)bh * S_ + qrow) * HD_;
  const bf16x8 qf0 = *(const bf16x8*)(qb + quad * 8);
  const bf16x8 qf1 = *(const bf16x8*)(qb + 32 + quad * 8);

  const f32x4 fz = {0.f, 0.f, 0.f, 0.f};
  f32x4 o[4];
#pragma unroll
  for (int d = 0; d < 4; ++d) o[d] = fz;
  float lsum = 0.f;

  const __bf16* gk[2];
  const __bf16* gv[2];
  int lofs[2];
#pragma unroll
  for (int i = 0; i < 2; ++i) {
    const int c = tid + i * 512;
    const int kr = c >> 3, kc = c & 7;
    gk[i] = Kp + ((size_t)bh * S_ + kr) * HD_ + ((kc ^ (kr & 7)) * 8);
    const int vr = c >> 4, vc = c & 15;
    gv[i] = Vtp + ((size_t)bh * HD_ + vr) * S_ + ((vc ^ (vr & 15)) * 8);
    lofs[i] = c * 8;
  }

#pragma unroll
  for (int i = 0; i < 2; ++i) {
    gl_lds16(gk[i], &Ks[0][lofs[i]]); gk[i] += 128 * HD_;
    gl_lds16(gv[i], &Vs[0][lofs[i]]); gv[i] += 128;
  }

  for (int kt = 0; kt < S_ / 128; ++kt) {
    const int cb = kt & 1;
    __syncthreads();
    if (kt + 1 < S_ / 128) {
#pragma unroll
      for (int i = 0; i < 2; ++i) {
        gl_lds16(gk[i], &Ks[cb ^ 1][lofs[i]]); gk[i] += 128 * HD_;
        gl_lds16(gv[i], &Vs[cb ^ 1][lofs[i]]); gv[i] += 128;
      }
    }

    f32x4 sa[8];
#pragma unroll
    for (int mt = 0; mt < 8; ++mt) {
      const int row = mt * 16 + r16;
      bf16x8 k0 = *(const bf16x8*)&Ks[cb][row * 64 + ((quad ^ (row & 7)) * 8)];
      bf16x8 k1 = *(const bf16x8*)&Ks[cb][row * 64 + (((4 + quad) ^ (row & 7)) * 8)];
      f32x4 t = fz;
      t = __builtin_amdgcn_mfma_f32_16x16x32_bf16(k0, qf0, t, 0, 0, 0);
      t = __builtin_amdgcn_mfma_f32_16x16x32_bf16(k1, qf1, t, 0, 0, 0);
      sa[mt] = t;
    }

    bf16x8 pf[4];
#pragma unroll
    for (int ks = 0; ks < 4; ++ks)
#pragma unroll
      for (int r = 0; r < 4; ++r) {
        float p0 = __builtin_amdgcn_exp2f(sa[2 * ks][r]);
        float p1 = __builtin_amdgcn_exp2f(sa[2 * ks + 1][r]);
        lsum += p0 + p1;
        pf[ks][r] = (__bf16)p0;
        pf[ks][4 + r] = (__bf16)p1;
      }

#pragma unroll
    for (int ks = 0; ks < 4; ++ks)
#pragma unroll
      for (int dt = 0; dt < 4; ++dt) {
        const int row = dt * 16 + r16;
        bf16x8 va = *(const bf16x8*)&Vs[cb][row * 128 + (((4 * ks + quad) ^ (row & 15)) * 8)];
        o[dt] = __builtin_amdgcn_mfma_f32_16x16x32_bf16(va, pf[ks], o[dt], 0, 0, 0);
      }
  }

  lsum += __shfl_xor(lsum, 16);
  lsum += __shfl_xor(lsum, 32);
  const float inv = 1.0f / lsum;
  const int b = bh >> 4, h = bh & 15;
  const int s = q0 + wave * 16 + r16;
#pragma unroll
  for (int dt = 0; dt < 4; ++dt) {
    bf16x4 ov;
#pragma unroll
    for (int r = 0; r < 4; ++r) ov[r] = (__bf16)(o[dt][r] * inv);
    *(bf16x4*)&ctx[((size_t)(b * S_ + s)) * DIM_ + h * 64 + dt * 16 + quad * 4] = ov;
  }
}

// ---------------- host launch ----------------
extern "C" void kernel_launch(void* const* d_in, const int* in_sizes, int n_in, void* d_out,
                              int out_size, void* d_ws, size_t ws_size, hipStream_t stream) {
  const float* x = (const float*)d_in[0];
  const float* qkv_w = (const float*)d_in[1];
  const float* qkv_b = (const float*)d_in[2];
  const float* proj_w = (const float*)d_in[3];
  const float* proj_b = (const float*)d_in[4];
  float* out = (float*)d_out;

  char* ws = (char*)d_ws;
  __bf16* Xb = (__bf16*)(ws);              // 8,388,608
  __bf16* Wb = (__bf16*)(ws + 8388608);    // 6,291,456
  __bf16* Pb = (__bf16*)(ws + 14680064);   // 2,097,152
  __bf16* Qp = (__bf16*)(ws + 16777216);   // 8,388,608 (pre-scaled by 0.125*log2e)
  __bf16* Kp = (__bf16*)(ws + 25165824);   // 8,388,608
  __bf16* Vt = (__bf16*)(ws + 33554432);   // 8,388,608 (transposed + key-permuted)
  __bf16* Cx = (__bf16*)(ws + 41943040);   // 8,388,608 -> ends 50,331,648

  cast_all<<<2048, 256, 0, stream>>>(x, qkv_w, proj_w, Xb, Wb, Pb);
  gemm_bt<0, 128><<<dim3(NQKV_ / 128, M_ / 128), 512, 0, stream>>>(Xb, Wb, qkv_b, Qp, Kp, Vt,
                                                                   nullptr);
  attn<<<dim3(S_ / 128, 32), 512, 0, stream>>>(Qp, Kp, Vt, Cx);
  gemm_bt<1, 64><<<dim3(DIM_ / 128, M_ / 64), 512, 0, stream>>>(Cx, Pb, proj_b, nullptr, nullptr,
                                                                nullptr, out);
}

// Round 8
// 173.938 us; speedup vs baseline: 1.0388x; 1.0388x over previous
//
#include <hip/hip_runtime.h>

#define DIM_ 1024
#define NH_ 16
#define HD_ 64
#define B_ 2
#define S_ 2048
#define M_ (B_ * S_)      // 4096
#define NQKV_ (3 * DIM_)  // 3072

typedef __attribute__((ext_vector_type(8))) __bf16 bf16x8;
typedef __attribute__((ext_vector_type(4))) __bf16 bf16x4;
typedef __attribute__((ext_vector_type(4))) float f32x4;

__device__ __forceinline__ void gl_lds16(const void* g, void* l) {
  __builtin_amdgcn_global_load_lds(
      (__attribute__((address_space(1))) void*)const_cast<void*>(g),
      (__attribute__((address_space(3))) void*)l, 16, 0, 0);
}

// ---------------- fused cast fp32 -> bf16 for x, qkv_w, proj_w ----------------
#define N4_X 1048576   // 4096*1024/4
#define N4_W1 786432   // 3072*1024/4
#define N4_W2 262144   // 1024*1024/4
__global__ __launch_bounds__(256) void cast_all(const float* __restrict__ x,
                                                const float* __restrict__ w1,
                                                const float* __restrict__ w2,
                                                __bf16* __restrict__ xb,
                                                __bf16* __restrict__ w1b,
                                                __bf16* __restrict__ w2b) {
  int i = blockIdx.x * 256 + threadIdx.x;
  const int stride = gridDim.x * 256;
  for (; i < N4_X + N4_W1 + N4_W2; i += stride) {
    const float4* src;
    bf16x4* dst;
    int j;
    if (i < N4_X) { src = (const float4*)x; dst = (bf16x4*)xb; j = i; }
    else if (i < N4_X + N4_W1) { src = (const float4*)w1; dst = (bf16x4*)w1b; j = i - N4_X; }
    else { src = (const float4*)w2; dst = (bf16x4*)w2b; j = i - (N4_X + N4_W1); }
    float4 v = src[j];
    bf16x4 o;
    o[0] = (__bf16)v.x; o[1] = (__bf16)v.y; o[2] = (__bf16)v.z; o[3] = (__bf16)v.w;
    dst[j] = o;
  }
}

// ---------------- BMx128 bf16 MFMA GEMM, BK=64, single-buffer (R6), 512 threads --------
// R7's double-buffer regressed: 64 KB LDS halved blocks/CU (m132 trap). Reverted.
// Y[m][n] = sum_k A[m][k] * Bw[n][k]  (+ bias[n])
// 8 waves: wm=wave>>1 (4 m-positions of MT*16 rows), wn=wave&1 (2 n-positions of 64).
// LDS tiles [BM|128][64], 16B-chunk XOR swizzle: chunk (r,c) at column c^(r&7).
// MODE 0 (BM=128): scatter Q (scaled 0.125*log2e), K as [bh][s][64]; V transposed+
//         key-permuted into Vt[bh][dh][slot] (slot = 32a+8q+4b+r for s=32a+16b+4q+r).
// MODE 1 (BM=64): write fp32 Cout[m][n] = Y + bias  (more blocks for short-N proj)
template <int MODE, int BM>
__global__ __launch_bounds__(512, 4) void gemm_bt(const __bf16* __restrict__ A,
                                                  const __bf16* __restrict__ Bw,
                                                  const float* __restrict__ bias,
                                                  __bf16* __restrict__ Qp, __bf16* __restrict__ Kp,
                                                  __bf16* __restrict__ Vt,
                                                  float* __restrict__ Cout) {
  constexpr int KD = 1024;
  constexpr int BN = 128;
  constexpr int MT = BM / 64;          // m-tiles (of 16 rows) per wave
  constexpr int NC = (BM + BN) / 64;   // 16B chunks staged per thread
  __shared__ __bf16 As[BM * 64];
  __shared__ __bf16 Bs[BN * 64];
  const int tid = threadIdx.x;
  const int lane = tid & 63;
  const int wave = tid >> 6;  // 0..7
  const int quad = lane >> 4;
  const int r16 = lane & 15;
  const int wm = wave >> 1;   // 0..3
  const int wn = wave & 1;    // 0..1
  const int m0 = blockIdx.y * BM;
  const int n0 = blockIdx.x * BN;

  const f32x4 fz = {0.f, 0.f, 0.f, 0.f};
  f32x4 acc[MT][4];
#pragma unroll
  for (int i = 0; i < MT; ++i)
#pragma unroll
    for (int j = 0; j < 4; ++j) acc[i][j] = fz;

  const __bf16* gp[NC];
  __bf16* lp[NC];
#pragma unroll
  for (int i = 0; i < NC; ++i) {
    const int c = tid + i * 512;
    if (c < BM * 8) {
      const int r = c >> 3, cc = c & 7;
      gp[i] = A + (size_t)(m0 + r) * KD + ((cc ^ (r & 7)) * 8);
      lp[i] = &As[c * 8];
    } else {
      const int c2 = c - BM * 8;
      const int r = c2 >> 3, cc = c2 & 7;
      gp[i] = Bw + (size_t)(n0 + r) * KD + ((cc ^ (r & 7)) * 8);
      lp[i] = &Bs[c2 * 8];
    }
  }

  for (int kt = 0; kt < KD / 64; ++kt) {
    __syncthreads();
#pragma unroll
    for (int i = 0; i < NC; ++i) { gl_lds16(gp[i], lp[i]); gp[i] += 64; }
    __syncthreads();

#pragma unroll
    for (int sub = 0; sub < 2; ++sub) {
      const int ch = ((sub * 4 + quad) ^ (r16 & 7)) * 8;
      bf16x8 af[MT], bfr[4];
#pragma unroll
      for (int mt = 0; mt < MT; ++mt)
        af[mt] = *(const bf16x8*)&As[(wm * MT * 16 + mt * 16 + r16) * 64 + ch];
#pragma unroll
      for (int nt = 0; nt < 4; ++nt)
        bfr[nt] = *(const bf16x8*)&Bs[(wn * 64 + nt * 16 + r16) * 64 + ch];
#pragma unroll
      for (int mt = 0; mt < MT; ++mt)
#pragma unroll
        for (int nt = 0; nt < 4; ++nt)
          acc[mt][nt] =
              __builtin_amdgcn_mfma_f32_16x16x32_bf16(af[mt], bfr[nt], acc[mt][nt], 0, 0, 0);
    }
  }

  if (MODE == 0) {
#pragma unroll
    for (int nt = 0; nt < 4; ++nt) {
      const int n = n0 + wn * 64 + nt * 16 + r16;
      const int sel = n >> 10;  // wave-uniform (n range is 64-aligned, 64-wide)
      const int h = (n >> 6) & 15;
      const int dh = n & 63;
      const float bs = bias[n];
      if (sel == 2) {
#pragma unroll
        for (int mt = 0; mt < MT; ++mt) {
          const int m = m0 + wm * MT * 16 + mt * 16 + quad * 4;
          const int b = m >> 11;
          const int s = m & 2047;
          const int slot = (s & ~31) | (((s >> 2) & 3) << 3) | (((s >> 4) & 1) << 2);
          bf16x4 ov;
#pragma unroll
          for (int r = 0; r < 4; ++r) ov[r] = (__bf16)(acc[mt][nt][r] + bs);
          *(bf16x4*)&Vt[((size_t)((b * NH_ + h) * HD_ + dh)) * S_ + slot] = ov;
        }
      } else {
        __bf16* dst = (sel == 0) ? Qp : Kp;
        const float mul = (sel == 0) ? 0.18033688011112042f : 1.0f;
#pragma unroll
        for (int mt = 0; mt < MT; ++mt) {
#pragma unroll
          for (int r = 0; r < 4; ++r) {
            const int m = m0 + wm * MT * 16 + mt * 16 + quad * 4 + r;
            const int b = m >> 11;
            const int s = m & 2047;
            dst[((size_t)((b * NH_ + h) * S_ + s)) * HD_ + dh] =
                (__bf16)((acc[mt][nt][r] + bs) * mul);
          }
        }
      }
    }
  } else {
#pragma unroll
    for (int nt = 0; nt < 4; ++nt) {
      const int n = n0 + wn * 64 + nt * 16 + r16;
      const float bs = bias[n];
#pragma unroll
      for (int mt = 0; mt < MT; ++mt) {
#pragma unroll
        for (int r = 0; r < 4; ++r) {
          const int m = m0 + wm * MT * 16 + mt * 16 + quad * 4 + r;
          Cout[(size_t)m * DIM_ + n] = acc[mt][nt][r] + bs;
        }
      }
    }
  }
}

// ---------------- flash attention, S^T form, 8 waves x 32q, double-buffered ----------------
// grid (S/256, B*H) = 256 blocks (1/CU, no tail); block 512 (8 waves x 32 queries).
// 32 q/wave doubles the register-resident operand width: 32 LDS reads now feed 64 MFMAs
// (reuse 2x), halving LDS traffic (R6's floor: 2.1 GB / 69 TB/s ~ 30 us -> ~15 us).
// VGPR kept ~100 by interleaving per-32-key groups: S-MFMAs -> exp2/pack -> PV-MFMAs,
// so only 4 f32x4 of scores are live (R4's mistake: 64 live score VGPRs).
// Q pre-scaled by 0.125*log2e; p = 2^s raw; P in registers; O^T = V^T P^T.
__global__ __launch_bounds__(512) void attn(const __bf16* __restrict__ Qp,
                                            const __bf16* __restrict__ Kp,
                                            const __bf16* __restrict__ Vtp,
                                            __bf16* __restrict__ ctx) {
  __shared__ __bf16 Ks[2][128 * 64];  // [key][dh], 16B-chunk XOR swizzle (8 chunks/row)
  __shared__ __bf16 Vs[2][64 * 128];  // [dh][perm key], XOR swizzle (16 chunks/row)
  const int tid = threadIdx.x;
  const int lane = tid & 63;
  const int wave = tid >> 6;  // 0..7
  const int quad = lane >> 4;
  const int r16 = lane & 15;
  const int bh = blockIdx.y;
  const int q0 = blockIdx.x * 256;

  bf16x8 qf[2][2];
#pragma unroll
  for (int g = 0; g < 2; ++g) {
    const __bf16* qb = Qp + ((size_t)bh * S_ + q0 + wave * 32 + g * 16 + r16) * HD_;
    qf[g][0] = *(const bf16x8*)(qb + quad * 8);
    qf[g][1] = *(const bf16x8*)(qb + 32 + quad * 8);
  }

  const f32x4 fz = {0.f, 0.f, 0.f, 0.f};
  f32x4 o[2][4];
  float lsum[2] = {0.f, 0.f};
#pragma unroll
  for (int g = 0; g < 2; ++g)
#pragma unroll
    for (int d = 0; d < 4; ++d) o[g][d] = fz;

  const __bf16* gk[2];
  const __bf16* gv[2];
  int lofs[2];
#pragma unroll
  for (int i = 0; i < 2; ++i) {
    const int c = tid + i * 512;
    const int kr = c >> 3, kc = c & 7;
    gk[i] = Kp + ((size_t)bh * S_ + kr) * HD_ + ((kc ^ (kr & 7)) * 8);
    const int vr = c >> 4, vc = c & 15;
    gv[i] = Vtp + ((size_t)bh * HD_ + vr) * S_ + ((vc ^ (vr & 15)) * 8);
    lofs[i] = c * 8;
  }

  // prefetch tile 0 into buffer 0
#pragma unroll
  for (int i = 0; i < 2; ++i) {
    gl_lds16(gk[i], &Ks[0][lofs[i]]); gk[i] += 128 * HD_;
    gl_lds16(gv[i], &Vs[0][lofs[i]]); gv[i] += 128;
  }

  for (int kt = 0; kt < S_ / 128; ++kt) {
    const int cb = kt & 1;
    __syncthreads();  // drains prefetch of tile kt; frees buffer cb^1
    if (kt + 1 < S_ / 128) {
#pragma unroll
      for (int i = 0; i < 2; ++i) {
        gl_lds16(gk[i], &Ks[cb ^ 1][lofs[i]]); gk[i] += 128 * HD_;
        gl_lds16(gv[i], &Vs[cb ^ 1][lofs[i]]); gv[i] += 128;
      }
    }

    // interleaved per-32-key groups: S-MFMA -> exp2/pack -> PV-MFMA
#pragma unroll
    for (int ks = 0; ks < 4; ++ks) {
      // S^T for keys 32ks..32ks+31: two 16-key m-tiles, both query groups
      f32x4 sa[2][2];  // [mt2][g]
#pragma unroll
      for (int mt2 = 0; mt2 < 2; ++mt2) {
        const int row = (ks * 2 + mt2) * 16 + r16;
        bf16x8 k0 = *(const bf16x8*)&Ks[cb][row * 64 + ((quad ^ (row & 7)) * 8)];
        bf16x8 k1 = *(const bf16x8*)&Ks[cb][row * 64 + (((4 + quad) ^ (row & 7)) * 8)];
#pragma unroll
        for (int g = 0; g < 2; ++g) {
          f32x4 t = fz;
          t = __builtin_amdgcn_mfma_f32_16x16x32_bf16(k0, qf[g][0], t, 0, 0, 0);
          t = __builtin_amdgcn_mfma_f32_16x16x32_bf16(k1, qf[g][1], t, 0, 0, 0);
          sa[mt2][g] = t;
        }
      }

      // p = 2^s; pack P^T B-frag: j<4 from tile 2ks (key 32ks+4q+j), j>=4 from 2ks+1
      bf16x8 pf[2];
#pragma unroll
      for (int g = 0; g < 2; ++g)
#pragma unroll
        for (int r = 0; r < 4; ++r) {
          float p0 = __builtin_amdgcn_exp2f(sa[0][g][r]);
          float p1 = __builtin_amdgcn_exp2f(sa[1][g][r]);
          lsum[g] += p0 + p1;
          pf[g][r] = (__bf16)p0;
          pf[g][4 + r] = (__bf16)p1;
        }

      // O^T += V^T P^T : one b128 V-fragment feeds both query groups
#pragma unroll
      for (int dt = 0; dt < 4; ++dt) {
        const int row = dt * 16 + r16;
        bf16x8 va = *(const bf16x8*)&Vs[cb][row * 128 + (((4 * ks + quad) ^ (row & 15)) * 8)];
#pragma unroll
        for (int g = 0; g < 2; ++g)
          o[g][dt] = __builtin_amdgcn_mfma_f32_16x16x32_bf16(va, pf[g], o[g][dt], 0, 0, 0);
      }
    }
  }

  const int b = bh >> 4, h = bh & 15;
#pragma unroll
  for (int g = 0; g < 2; ++g) {
    float l = lsum[g];
    l += __shfl_xor(l, 16);
    l += __shfl_xor(l, 32);
    const float inv = 1.0f / l;
    const int s = q0 + wave * 32 + g * 16 + r16;
#pragma unroll
    for (int dt = 0; dt < 4; ++dt) {
      bf16x4 ov;
#pragma unroll
      for (int r = 0; r < 4; ++r) ov[r] = (__bf16)(o[g][dt][r] * inv);
      *(bf16x4*)&ctx[((size_t)(b * S_ + s)) * DIM_ + h * 64 + dt * 16 + quad * 4] = ov;
    }
  }
}

// ---------------- host launch ----------------
extern "C" void kernel_launch(void* const* d_in, const int* in_sizes, int n_in, void* d_out,
                              int out_size, void* d_ws, size_t ws_size, hipStream_t stream) {
  const float* x = (const float*)d_in[0];
  const float* qkv_w = (const float*)d_in[1];
  const float* qkv_b = (const float*)d_in[2];
  const float* proj_w = (const float*)d_in[3];
  const float* proj_b = (const float*)d_in[4];
  float* out = (float*)d_out;

  char* ws = (char*)d_ws;
  __bf16* Xb = (__bf16*)(ws);              // 8,388,608
  __bf16* Wb = (__bf16*)(ws + 8388608);    // 6,291,456
  __bf16* Pb = (__bf16*)(ws + 14680064);   // 2,097,152
  __bf16* Qp = (__bf16*)(ws + 16777216);   // 8,388,608 (pre-scaled by 0.125*log2e)
  __bf16* Kp = (__bf16*)(ws + 25165824);   // 8,388,608
  __bf16* Vt = (__bf16*)(ws + 33554432);   // 8,388,608 (transposed + key-permuted)
  __bf16* Cx = (__bf16*)(ws + 41943040);   // 8,388,608 -> ends 50,331,648

  cast_all<<<2048, 256, 0, stream>>>(x, qkv_w, proj_w, Xb, Wb, Pb);
  gemm_bt<0, 128><<<dim3(NQKV_ / 128, M_ / 128), 512, 0, stream>>>(Xb, Wb, qkv_b, Qp, Kp, Vt,
                                                                   nullptr);
  attn<<<dim3(S_ / 256, 32), 512, 0, stream>>>(Qp, Kp, Vt, Cx);
  gemm_bt<1, 64><<<dim3(DIM_ / 128, M_ / 64), 512, 0, stream>>>(Cx, Pb, proj_b, nullptr, nullptr,
                                                                nullptr, out);
}

// Round 10
// 173.932 us; speedup vs baseline: 1.0388x; 1.0000x over previous
//
#include <hip/hip_runtime.h>

#define DIM_ 1024
#define NH_ 16
#define HD_ 64
#define B_ 2
#define S_ 2048
#define M_ (B_ * S_)      // 4096
#define NQKV_ (3 * DIM_)  // 3072

typedef __attribute__((ext_vector_type(8))) __bf16 bf16x8;
typedef __attribute__((ext_vector_type(4))) __bf16 bf16x4;
typedef __attribute__((ext_vector_type(4))) float f32x4;

__device__ __forceinline__ void gl_lds16(const void* g, void* l) {
  __builtin_amdgcn_global_load_lds(
      (__attribute__((address_space(1))) void*)const_cast<void*>(g),
      (__attribute__((address_space(3))) void*)l, 16, 0, 0);
}

// ---------------- fused cast fp32 -> bf16 for x, qkv_w, proj_w ----------------
#define N4_X 1048576   // 4096*1024/4
#define N4_W1 786432   // 3072*1024/4
#define N4_W2 262144   // 1024*1024/4
__global__ __launch_bounds__(256) void cast_all(const float* __restrict__ x,
                                                const float* __restrict__ w1,
                                                const float* __restrict__ w2,
                                                __bf16* __restrict__ xb,
                                                __bf16* __restrict__ w1b,
                                                __bf16* __restrict__ w2b) {
  int i = blockIdx.x * 256 + threadIdx.x;
  const int stride = gridDim.x * 256;
  for (; i < N4_X + N4_W1 + N4_W2; i += stride) {
    const float4* src;
    bf16x4* dst;
    int j;
    if (i < N4_X) { src = (const float4*)x; dst = (bf16x4*)xb; j = i; }
    else if (i < N4_X + N4_W1) { src = (const float4*)w1; dst = (bf16x4*)w1b; j = i - N4_X; }
    else { src = (const float4*)w2; dst = (bf16x4*)w2b; j = i - (N4_X + N4_W1); }
    float4 v = src[j];
    bf16x4 o;
    o[0] = (__bf16)v.x; o[1] = (__bf16)v.y; o[2] = (__bf16)v.z; o[3] = (__bf16)v.w;
    dst[j] = o;
  }
}

// ---------------- BMx128 bf16 MFMA GEMM, BK=64, single-buffer (R6), 512 threads --------
// Y[m][n] = sum_k A[m][k] * Bw[n][k]  (+ bias[n])
// MODE 0 (BM=128): scatter Q (scaled 0.125*log2e), K as [bh][s][64]; V transposed+
//         key-permuted into Vt[bh][dh][slot] (slot = 32a+8q+4b+r for s=32a+16b+4q+r).
// MODE 1 (BM=64): write fp32 Cout[m][n] = Y + bias
template <int MODE, int BM>
__global__ __launch_bounds__(512, 4) void gemm_bt(const __bf16* __restrict__ A,
                                                  const __bf16* __restrict__ Bw,
                                                  const float* __restrict__ bias,
                                                  __bf16* __restrict__ Qp, __bf16* __restrict__ Kp,
                                                  __bf16* __restrict__ Vt,
                                                  float* __restrict__ Cout) {
  constexpr int KD = 1024;
  constexpr int BN = 128;
  constexpr int MT = BM / 64;
  constexpr int NC = (BM + BN) / 64;
  __shared__ __bf16 As[BM * 64];
  __shared__ __bf16 Bs[BN * 64];
  const int tid = threadIdx.x;
  const int lane = tid & 63;
  const int wave = tid >> 6;
  const int quad = lane >> 4;
  const int r16 = lane & 15;
  const int wm = wave >> 1;
  const int wn = wave & 1;
  const int m0 = blockIdx.y * BM;
  const int n0 = blockIdx.x * BN;

  const f32x4 fz = {0.f, 0.f, 0.f, 0.f};
  f32x4 acc[MT][4];
#pragma unroll
  for (int i = 0; i < MT; ++i)
#pragma unroll
    for (int j = 0; j < 4; ++j) acc[i][j] = fz;

  const __bf16* gp[NC];
  __bf16* lp[NC];
#pragma unroll
  for (int i = 0; i < NC; ++i) {
    const int c = tid + i * 512;
    if (c < BM * 8) {
      const int r = c >> 3, cc = c & 7;
      gp[i] = A + (size_t)(m0 + r) * KD + ((cc ^ (r & 7)) * 8);
      lp[i] = &As[c * 8];
    } else {
      const int c2 = c - BM * 8;
      const int r = c2 >> 3, cc = c2 & 7;
      gp[i] = Bw + (size_t)(n0 + r) * KD + ((cc ^ (r & 7)) * 8);
      lp[i] = &Bs[c2 * 8];
    }
  }

  for (int kt = 0; kt < KD / 64; ++kt) {
    __syncthreads();
#pragma unroll
    for (int i = 0; i < NC; ++i) { gl_lds16(gp[i], lp[i]); gp[i] += 64; }
    __syncthreads();

#pragma unroll
    for (int sub = 0; sub < 2; ++sub) {
      const int ch = ((sub * 4 + quad) ^ (r16 & 7)) * 8;
      bf16x8 af[MT], bfr[4];
#pragma unroll
      for (int mt = 0; mt < MT; ++mt)
        af[mt] = *(const bf16x8*)&As[(wm * MT * 16 + mt * 16 + r16) * 64 + ch];
#pragma unroll
      for (int nt = 0; nt < 4; ++nt)
        bfr[nt] = *(const bf16x8*)&Bs[(wn * 64 + nt * 16 + r16) * 64 + ch];
#pragma unroll
      for (int mt = 0; mt < MT; ++mt)
#pragma unroll
        for (int nt = 0; nt < 4; ++nt)
          acc[mt][nt] =
              __builtin_amdgcn_mfma_f32_16x16x32_bf16(af[mt], bfr[nt], acc[mt][nt], 0, 0, 0);
    }
  }

  if (MODE == 0) {
#pragma unroll
    for (int nt = 0; nt < 4; ++nt) {
      const int n = n0 + wn * 64 + nt * 16 + r16;
      const int sel = n >> 10;
      const int h = (n >> 6) & 15;
      const int dh = n & 63;
      const float bs = bias[n];
      if (sel == 2) {
#pragma unroll
        for (int mt = 0; mt < MT; ++mt) {
          const int m = m0 + wm * MT * 16 + mt * 16 + quad * 4;
          const int b = m >> 11;
          const int s = m & 2047;
          const int slot = (s & ~31) | (((s >> 2) & 3) << 3) | (((s >> 4) & 1) << 2);
          bf16x4 ov;
#pragma unroll
          for (int r = 0; r < 4; ++r) ov[r] = (__bf16)(acc[mt][nt][r] + bs);
          *(bf16x4*)&Vt[((size_t)((b * NH_ + h) * HD_ + dh)) * S_ + slot] = ov;
        }
      } else {
        __bf16* dst = (sel == 0) ? Qp : Kp;
        const float mul = (sel == 0) ? 0.18033688011112042f : 1.0f;
#pragma unroll
        for (int mt = 0; mt < MT; ++mt) {
#pragma unroll
          for (int r = 0; r < 4; ++r) {
            const int m = m0 + wm * MT * 16 + mt * 16 + quad * 4 + r;
            const int b = m >> 11;
            const int s = m & 2047;
            dst[((size_t)((b * NH_ + h) * S_ + s)) * HD_ + dh] =
                (__bf16)((acc[mt][nt][r] + bs) * mul);
          }
        }
      }
    }
  } else {
#pragma unroll
    for (int nt = 0; nt < 4; ++nt) {
      const int n = n0 + wn * 64 + nt * 16 + r16;
      const float bs = bias[n];
#pragma unroll
      for (int mt = 0; mt < MT; ++mt) {
#pragma unroll
        for (int r = 0; r < 4; ++r) {
          const int m = m0 + wm * MT * 16 + mt * 16 + quad * 4 + r;
          Cout[(size_t)m * DIM_ + n] = acc[mt][nt][r] + bs;
        }
      }
    }
  }
}

// ---------------- flash attention: 32q/wave + in-block key-split ----------------
// grid (S/128=16, B*H) = 512 blocks (2/CU => 16 waves/CU); block 512 = 8 waves.
// wave = (kh = wave>>2: key half, qg = wave&3: 32-query group). Each wave processes
// its 32 queries against its 1024-key half in 16 tiles of 64 keys (dbuf LDS, 64 KB).
// 32q/wave: 16 LDS b128 reads feed 32 MFMAs (2x reuse vs 16q) while the split keeps
// 4096 waves total (R8's mistake: 32q/wave without split = only 2048 waves = 2/SIMD).
// Max-free softmax (p = 2^s raw, Q pre-scaled 0.125*log2e) makes halves combine
// ADDITIVELY: one fp32 LDS exchange in the epilogue, no rescaling.
// R9 bug fixed here: K prefetch pointers advance 64*HD_ per 64-key tile (K is
// [key][dh]); only V advances by 64 (Vt is [dh][slot], slots contiguous).
__global__ __launch_bounds__(512, 4) void attn(const __bf16* __restrict__ Qp,
                                               const __bf16* __restrict__ Kp,
                                               const __bf16* __restrict__ Vtp,
                                               __bf16* __restrict__ ctx) {
  // [buf][K=0/V=1][half][64x64 tile, XOR-swizzled 8-chunk rows]; also epilogue xch space
  __shared__ __bf16 smem[2][2][2][64 * 64];
  const int tid = threadIdx.x;
  const int lane = tid & 63;
  const int wave = tid >> 6;
  const int quad = lane >> 4;
  const int r16 = lane & 15;
  const int qg = wave & 3;
  const int kh = wave >> 2;
  const int bh = blockIdx.y;
  const int q0 = blockIdx.x * 128;

  bf16x8 qf[2][2];
#pragma unroll
  for (int g = 0; g < 2; ++g) {
    const __bf16* qb = Qp + ((size_t)bh * S_ + q0 + qg * 32 + g * 16 + r16) * HD_;
    qf[g][0] = *(const bf16x8*)(qb + quad * 8);
    qf[g][1] = *(const bf16x8*)(qb + 32 + quad * 8);
  }

  const f32x4 fz = {0.f, 0.f, 0.f, 0.f};
  f32x4 o[2][4];
  float lsum[2] = {0.f, 0.f};
#pragma unroll
  for (int g = 0; g < 2; ++g)
#pragma unroll
    for (int d = 0; d < 4; ++d) o[g][d] = fz;

  // staging: per kt, 4 tiles of 64x64 (K-lo,K-hi,V-lo,V-hi) = 2048 chunks; 4/thread.
  const __bf16* gp[4];
  int gstep[4], lkv[4], lhh[4], lof[4];
#pragma unroll
  for (int i = 0; i < 4; ++i) {
    const int c = tid + i * 512;
    if (c < 1024) {  // K chunks: K is [key][dh] -> next 64-key tile is +64*HD_
      const int hh = c >> 9, c2 = c & 511;
      const int kr = c2 >> 3, kc = c2 & 7;
      gp[i] = Kp + ((size_t)bh * S_ + hh * 1024 + kr) * HD_ + ((kc ^ (kr & 7)) * 8);
      gstep[i] = 64 * HD_;
      lkv[i] = 0; lhh[i] = hh; lof[i] = c2 * 8;
    } else {  // V chunks: Vt is [dh][slot] -> next 64-slot tile is +64
      const int c1 = c - 1024;
      const int hh = c1 >> 9, c2 = c1 & 511;
      const int vr = c2 >> 3, vc = c2 & 7;
      gp[i] = Vtp + ((size_t)bh * HD_ + vr) * S_ + hh * 1024 + ((vc ^ (vr & 7)) * 8);
      gstep[i] = 64;
      lkv[i] = 1; lhh[i] = hh; lof[i] = c2 * 8;
    }
  }

  // prefetch kt=0 into buffer 0
#pragma unroll
  for (int i = 0; i < 4; ++i) {
    gl_lds16(gp[i], &smem[0][lkv[i]][lhh[i]][lof[i]]);
    gp[i] += gstep[i];
  }

  for (int kt = 0; kt < 16; ++kt) {
    const int cb = kt & 1;
    __syncthreads();  // drains prefetch of kt (issued a full compute phase ago)
    if (kt + 1 < 16) {
#pragma unroll
      for (int i = 0; i < 4; ++i) {
        gl_lds16(gp[i], &smem[cb ^ 1][lkv[i]][lhh[i]][lof[i]]);
        gp[i] += gstep[i];
      }
    }

    const __bf16* Kt = &smem[cb][0][kh][0];
    const __bf16* Vt2 = &smem[cb][1][kh][0];
#pragma unroll
    for (int ks = 0; ks < 2; ++ks) {
      // S^T for this tile's keys [32ks, 32ks+32): 2 m-tiles x both q-groups
      f32x4 sa[2][2];
#pragma unroll
      for (int mt2 = 0; mt2 < 2; ++mt2) {
        const int row = (ks * 2 + mt2) * 16 + r16;
        bf16x8 k0 = *(const bf16x8*)&Kt[row * 64 + ((quad ^ (row & 7)) * 8)];
        bf16x8 k1 = *(const bf16x8*)&Kt[row * 64 + (((4 + quad) ^ (row & 7)) * 8)];
#pragma unroll
        for (int g = 0; g < 2; ++g) {
          f32x4 t = fz;
          t = __builtin_amdgcn_mfma_f32_16x16x32_bf16(k0, qf[g][0], t, 0, 0, 0);
          t = __builtin_amdgcn_mfma_f32_16x16x32_bf16(k1, qf[g][1], t, 0, 0, 0);
          sa[mt2][g] = t;
        }
      }

      bf16x8 pf[2];
#pragma unroll
      for (int g = 0; g < 2; ++g)
#pragma unroll
        for (int r = 0; r < 4; ++r) {
          float p0 = __builtin_amdgcn_exp2f(sa[0][g][r]);
          float p1 = __builtin_amdgcn_exp2f(sa[1][g][r]);
          lsum[g] += p0 + p1;
          pf[g][r] = (__bf16)p0;
          pf[g][4 + r] = (__bf16)p1;
        }

#pragma unroll
      for (int dt = 0; dt < 4; ++dt) {
        const int row = dt * 16 + r16;
        bf16x8 va = *(const bf16x8*)&Vt2[row * 64 + (((ks * 4 + quad) ^ (row & 7)) * 8)];
#pragma unroll
        for (int g = 0; g < 2; ++g)
          o[g][dt] = __builtin_amdgcn_mfma_f32_16x16x32_bf16(va, pf[g], o[g][dt], 0, 0, 0);
      }
    }
  }

  // full per-query l for this half (quads hold disjoint keys)
#pragma unroll
  for (int g = 0; g < 2; ++g) {
    lsum[g] += __shfl_xor(lsum[g], 16);
    lsum[g] += __shfl_xor(lsum[g], 32);
  }

  // additive cross-half combine via LDS: kh==1 publishes, kh==0 merges & stores
  float* xch = (float*)smem;  // 64 KB; used: 4 waves * (8 KB o + 0.5 KB l) = 34 KB
  __syncthreads();  // all tile reads done; LDS reusable
  if (kh == 1) {
#pragma unroll
    for (int g = 0; g < 2; ++g) {
#pragma unroll
      for (int dt = 0; dt < 4; ++dt)
        *(f32x4*)&xch[(qg * 8 + g * 4 + dt) * 256 + lane * 4] = o[g][dt];
      xch[8192 + qg * 128 + g * 64 + lane] = lsum[g];
    }
  }
  __syncthreads();
  if (kh == 0) {
    const int b = bh >> 4, h = bh & 15;
#pragma unroll
    for (int g = 0; g < 2; ++g) {
      const float l = lsum[g] + xch[8192 + qg * 128 + g * 64 + lane];
      const float inv = 1.0f / l;
      const int s = q0 + qg * 32 + g * 16 + r16;
#pragma unroll
      for (int dt = 0; dt < 4; ++dt) {
        f32x4 op = *(const f32x4*)&xch[(qg * 8 + g * 4 + dt) * 256 + lane * 4];
        bf16x4 ov;
#pragma unroll
        for (int r = 0; r < 4; ++r) ov[r] = (__bf16)((o[g][dt][r] + op[r]) * inv);
        *(bf16x4*)&ctx[((size_t)(b * S_ + s)) * DIM_ + h * 64 + dt * 16 + quad * 4] = ov;
      }
    }
  }
}

// ---------------- host launch ----------------
extern "C" void kernel_launch(void* const* d_in, const int* in_sizes, int n_in, void* d_out,
                              int out_size, void* d_ws, size_t ws_size, hipStream_t stream) {
  const float* x = (const float*)d_in[0];
  const float* qkv_w = (const float*)d_in[1];
  const float* qkv_b = (const float*)d_in[2];
  const float* proj_w = (const float*)d_in[3];
  const float* proj_b = (const float*)d_in[4];
  float* out = (float*)d_out;

  char* ws = (char*)d_ws;
  __bf16* Xb = (__bf16*)(ws);              // 8,388,608
  __bf16* Wb = (__bf16*)(ws + 8388608);    // 6,291,456
  __bf16* Pb = (__bf16*)(ws + 14680064);   // 2,097,152
  __bf16* Qp = (__bf16*)(ws + 16777216);   // 8,388,608 (pre-scaled by 0.125*log2e)
  __bf16* Kp = (__bf16*)(ws + 25165824);   // 8,388,608
  __bf16* Vt = (__bf16*)(ws + 33554432);   // 8,388,608 (transposed + key-permuted)
  __bf16* Cx = (__bf16*)(ws + 41943040);   // 8,388,608 -> ends 50,331,648

  cast_all<<<2048, 256, 0, stream>>>(x, qkv_w, proj_w, Xb, Wb, Pb);
  gemm_bt<0, 128><<<dim3(NQKV_ / 128, M_ / 128), 512, 0, stream>>>(Xb, Wb, qkv_b, Qp, Kp, Vt,
                                                                   nullptr);
  attn<<<dim3(S_ / 128, 32), 512, 0, stream>>>(Qp, Kp, Vt, Cx);
  gemm_bt<1, 64><<<dim3(DIM_ / 128, M_ / 64), 512, 0, stream>>>(Cx, Pb, proj_b, nullptr, nullptr,
                                                                nullptr, out);
}